// Round 3
// baseline (211.245 us; speedup 1.0000x reference)
//
#include <hip/hip_runtime.h>

#define BB   4
#define CC   256
#define HH   128
#define WW   128
#define PAD  4
#define KOUT 81

#define TH   8        // output rows per block (one per wave)
#define SW   16       // output cols per block (one MFMA M-tile)
#define KC   32       // channels per chunk (one MFMA K)
#define NCHUNK (CC / KC)
#define AK   40       // padded K-stride per LDS point (80 B: 16B-aligned, stride-20-words reads conflict-free)
#define SCP  130      // epilogue plane stride in floats: 128 slots + 2 pad (bank-decorrelates k)

typedef _Float16 half8 __attribute__((ext_vector_type(8)));
typedef float    f32x4 __attribute__((ext_vector_type(4)));

__global__ __launch_bounds__(512, 4)
void corr_mfma5(const float* __restrict__ i1,
                const float* __restrict__ i2,
                float* __restrict__ out)
{
    // One shared pool, three views:
    //   staging phase: Ald (10240 B) + Bld (40960 B), [pt][ch] AK-strided f16
    //   epilogue:      sc = [81][SCP] f32 plane buffer (42120 B), reuses the pool
    __shared__ __align__(16) char smem[51200];
    _Float16* const Ald = (_Float16*)smem;
    _Float16* const Bld = (_Float16*)(smem + 10240);
    float*    const sc  = (float*)smem;

    const int t    = threadIdx.x;
    const int wave = t >> 6;
    const int lane = t & 63;
    const int l15  = lane & 15;
    const int quad = lane >> 4;

    // ---- XCD-chunked block swizzle (kept from r2: FETCH 196->71 MB) ----
    const int raw     = blockIdx.x + 8 * blockIdx.y + 128 * blockIdx.z;
    const int logical = (raw & 7) * 64 + (raw >> 3);   // bijective: 512 = 8*64
    const int b  = logical >> 7;
    const int h0 = ((logical >> 3) & 15) * TH;
    const int w0 = (logical & 7) * SW;

    const size_t strideC = (size_t)HH * WW;
    const float* i1b = i1 + (size_t)b * CC * strideC;
    const float* i2b = i2 + (size_t)b * CC * strideC;

    // ---- staging role: each thread owns a (4-col x 8-channel) granule ----
    bool valid;
    const float* gp;
    _Float16* ld0;

    if (t < 384) {
        const int g   = t % 6;           // col-group: cols w0-4+4g .. +3
        const int t6  = t / 6;           // 0..63
        const int ch8 = t6 & 3;          // channel sub-block (x8)
        const int sr  = t6 >> 2;         // B tile row 0..15
        const int row  = h0 - PAD + sr;
        const int col0 = w0 - PAD + 4 * g;
        valid = (row >= 0) && (row < HH) && (col0 >= 0) && (col0 + 3 < WW);
        gp  = i2b + (size_t)(valid ? row : 0) * WW + (valid ? col0 : 0)
                  + (size_t)ch8 * 8 * strideC;
        ld0 = &Bld[(sr * 32 + 4 * g) * AK + ch8 * 8];
    } else {
        const int i   = t - 384;
        const int g   = i & 3;           // col-group: cols w0+4g .. +3
        const int t4  = i >> 2;          // 0..31
        const int ch8 = t4 & 3;
        const int sr  = t4 >> 2;         // A tile row 0..7
        valid = true;
        gp  = i1b + (size_t)(h0 + sr) * WW + (w0 + 4 * g)
                  + (size_t)ch8 * 8 * strideC;
        ld0 = &Ald[(sr * 16 + 4 * g) * AK + ch8 * 8];
    }

    f32x4 acc[9][2];
#pragma unroll
    for (int dy = 0; dy < 9; ++dy) {
        acc[dy][0] = (f32x4){0.f, 0.f, 0.f, 0.f};
        acc[dy][1] = (f32x4){0.f, 0.f, 0.f, 0.f};
    }

    // ---- prologue: stage chunk 0; invalid threads zero their slots ONCE ----
    if (valid) {
        f32x4 L[8];
#pragma unroll
        for (int j = 0; j < 8; ++j)
            L[j] = *(const f32x4*)(gp + (size_t)j * strideC);
#pragma unroll
        for (int i = 0; i < 4; ++i) {
            half8 hvp;
#pragma unroll
            for (int k = 0; k < 8; ++k) hvp[k] = (_Float16)L[k][i];
            *(half8*)(ld0 + i * AK) = hvp;
        }
    } else {
        const half8 z = (half8){0, 0, 0, 0, 0, 0, 0, 0};
#pragma unroll
        for (int i = 0; i < 4; ++i)
            *(half8*)(ld0 + i * AK) = z;
    }
    __syncthreads();

    half8 hv[4];   // converted next-chunk data: ONLY 16 VGPRs live across the barrier

#pragma unroll 1
    for (int ch = 0; ch < NCHUNK; ++ch) {
        const bool more = (ch + 1 < NCHUNK);

        // ---- issue next chunk's loads (no waits here) ----
        f32x4 L[8];
        if (valid && more) {
            const float* g = gp + (size_t)(ch + 1) * KC * strideC;
#pragma unroll
            for (int j = 0; j < 8; ++j)
                L[j] = *(const f32x4*)(g + (size_t)j * strideC);
        }

        const half8 a = *(const half8*)&Ald[(wave * 16 + l15) * AK + quad * 8];

        // ---- first compute half (dy 0..4) covers the load latency ----
#pragma unroll
        for (int dy = 0; dy < 5; ++dy) {
            const int r = wave + dy;
            const half8 b0 = *(const half8*)&Bld[(r * 32 + l15) * AK + quad * 8];
            acc[dy][0] = __builtin_amdgcn_mfma_f32_16x16x32_f16(a, b0, acc[dy][0], 0, 0, 0);
            const half8 b1 = *(const half8*)&Bld[(r * 32 + 16 + l15) * AK + quad * 8];
            acc[dy][1] = __builtin_amdgcn_mfma_f32_16x16x32_f16(a, b1, acc[dy][1], 0, 0, 0);
        }

        // ---- mid-loop convert: retires L[8] (32 VGPRs) down to hv[4] (16) ----
        if (valid && more) {
#pragma unroll
            for (int i = 0; i < 4; ++i) {
#pragma unroll
                for (int k = 0; k < 4; ++k) hv[i][k] = (_Float16)L[k][i];
            }
#pragma unroll
            for (int i = 0; i < 4; ++i) {
#pragma unroll
                for (int k = 4; k < 8; ++k) hv[i][k] = (_Float16)L[k][i];
            }
        }

        // ---- second compute half (dy 5..8) ----
#pragma unroll
        for (int dy = 5; dy < 9; ++dy) {
            const int r = wave + dy;
            const half8 b0 = *(const half8*)&Bld[(r * 32 + l15) * AK + quad * 8];
            acc[dy][0] = __builtin_amdgcn_mfma_f32_16x16x32_f16(a, b0, acc[dy][0], 0, 0, 0);
            const half8 b1 = *(const half8*)&Bld[(r * 32 + 16 + l15) * AK + quad * 8];
            acc[dy][1] = __builtin_amdgcn_mfma_f32_16x16x32_f16(a, b1, acc[dy][1], 0, 0, 0);
        }

        if (more) {
            __syncthreads();   // all waves done reading LDS for chunk ch
            if (valid) {
#pragma unroll
                for (int i = 0; i < 4; ++i)
                    *(half8*)(ld0 + i * AK) = hv[i];
            }
            __syncthreads();   // chunk ch+1 visible
        }
    }

    // ---- epilogue: scatter acc into LDS plane buffer, then coalesced stores ----
    // D[p][q]: p = quad*4+reg, q = l15 + 16*tt, dx = q - p, plane k = dy*9+dx.
    __syncthreads();   // last chunk's LDS reads done before aliasing smem as sc
#pragma unroll
    for (int dy = 0; dy < 9; ++dy) {
#pragma unroll
        for (int tt = 0; tt < 2; ++tt) {
#pragma unroll
            for (int reg = 0; reg < 4; ++reg) {
                const int p  = quad * 4 + reg;
                const int dx = l15 + 16 * tt - p;
                if (dx >= 0 && dx <= 8)
                    sc[(dy * 9 + dx) * SCP + wave * 16 + p] = acc[dy][tt][reg];
            }
        }
    }
    __syncthreads();

    // each wave streams whole planes: 2 wave-stores per plane, 4x64B runs each
    for (int k = wave; k < KOUT; k += TH) {
        const float v0 = sc[k * SCP + lane];
        const float v1 = sc[k * SCP + 64 + lane];
        float* op = out + (((size_t)b * KOUT + k) * HH + h0) * WW + w0;
        op[(size_t)(lane >> 4) * WW + (lane & 15)] = v0;
        op[(size_t)(4 + (lane >> 4)) * WW + (lane & 15)] = v1;
    }
}

extern "C" void kernel_launch(void* const* d_in, const int* in_sizes, int n_in,
                              void* d_out, int out_size, void* d_ws, size_t ws_size,
                              hipStream_t stream)
{
    (void)in_sizes; (void)n_in; (void)d_ws; (void)ws_size; (void)out_size;
    const float* i1 = (const float*)d_in[0];
    const float* i2 = (const float*)d_in[1];
    float* out = (float*)d_out;

    dim3 grid(WW / SW, HH / TH, BB);   // (8, 16, 4) = 512 blocks, 2 per CU
    dim3 block(512);
    corr_mfma5<<<grid, block, 0, stream>>>(i1, i2, out);
}

// Round 4
// 190.012 us; speedup vs baseline: 1.1117x; 1.1117x over previous
//
#include <hip/hip_runtime.h>

#define BB   4
#define CC   256
#define HH   128
#define WW   128
#define PAD  4
#define KOUT 81

#define TH   4        // output rows per block (4 rows x 2 dy-halves = 8 waves)
#define SW   16       // output cols per block (one MFMA M-tile)
#define KC   32       // channels per chunk (one MFMA K)
#define NCHUNK (CC / KC)
#define AK   40       // padded K-stride per LDS point (80 B: 16B-aligned, conflict-free reads)
#define BROWS (TH + 8)   // 12 staged B rows

typedef _Float16 half8 __attribute__((ext_vector_type(8)));
typedef float    f32x4 __attribute__((ext_vector_type(4)));

__global__ __launch_bounds__(512, 4)
void corr_mfma6(const float* __restrict__ i1,
                const float* __restrict__ i2,
                float* __restrict__ out)
{
    // LDS: [pt][ch], AK-strided f16. A: 4 rows x 16 m. B: 12 rows x 32 slots
    // (slots 0..23 written; 24..31 read-as-garbage -> only feeds dx>8, never stored).
    __shared__ __align__(16) _Float16 Ald[64 * AK];    //  5120 B
    __shared__ __align__(16) _Float16 Bld[384 * AK];   // 30720 B  (35840 total)

    const int t    = threadIdx.x;
    const int wave = t >> 6;
    const int lane = t & 63;
    const int l15  = lane & 15;
    const int quad = lane >> 4;
    const int wr   = wave >> 1;   // output row within tile (0..3)
    const int wd   = wave & 1;    // dy half: 0 -> dy 0..4, 1 -> dy 5..8

    // ---- XCD-chunked block swizzle (r2-proven: FETCH 196->71 MB) ----
    // grid (8,32,4): raw linear id; XCD = raw%8. Remap so each XCD owns a
    // contiguous 64-row band of one batch (sequential row streams, band fits L2).
    const int raw     = blockIdx.x + 8 * blockIdx.y + 256 * blockIdx.z;
    const int logical = (raw & 7) * 128 + (raw >> 3);   // bijective: 1024 = 8*128
    const int b  = logical >> 8;
    const int h0 = ((logical >> 3) & 31) * TH;
    const int w0 = (logical & 7) * SW;

    const size_t strideC = (size_t)HH * WW;
    const float* i1b = i1 + (size_t)b * CC * strideC;
    const float* i2b = i2 + (size_t)b * CC * strideC;

    // ---- staging role: threads 0..351 own a (4-col x 8-channel) granule ----
    // B: threads 0..287 = 12 rows x 6 col-groups x 4 ch8-groups
    // A: threads 288..351 = 4 rows x 4 col-groups x 4 ch8-groups
    // threads 352..511: compute-only.
    bool stager, valid;
    const float* gp;
    _Float16* ld0;

    if (t < 288) {
        stager = true;
        const int g   = t % 6;           // col-group: cols w0-4+4g .. +3
        const int t6  = t / 6;           // 0..47
        const int ch8 = t6 & 3;          // channel sub-block (x8)
        const int sr  = t6 >> 2;         // B tile row 0..11
        const int row  = h0 - PAD + sr;
        const int col0 = w0 - PAD + 4 * g;
        valid = (row >= 0) && (row < HH) && (col0 >= 0) && (col0 + 3 < WW);
        gp  = i2b + (size_t)(valid ? row : 0) * WW + (valid ? col0 : 0)
                  + (size_t)ch8 * 8 * strideC;
        ld0 = &Bld[(sr * 32 + 4 * g) * AK + ch8 * 8];
    } else if (t < 352) {
        stager = true;
        const int i   = t - 288;
        const int g   = i & 3;           // col-group: cols w0+4g .. +3
        const int t4  = i >> 2;          // 0..15
        const int ch8 = t4 & 3;
        const int sr  = t4 >> 2;         // A tile row 0..3
        valid = true;
        gp  = i1b + (size_t)(h0 + sr) * WW + (w0 + 4 * g)
                  + (size_t)ch8 * 8 * strideC;
        ld0 = &Ald[(sr * 16 + 4 * g) * AK + ch8 * 8];
    } else {
        stager = false;
        valid  = false;
        gp  = i1b;
        ld0 = &Ald[0];
    }

    // dy-split accumulator: 5x2x4 = 40 regs (wd=1 uses 4x2x4)
    f32x4 acc[5][2];
#pragma unroll
    for (int j = 0; j < 5; ++j) {
        acc[j][0] = (f32x4){0.f, 0.f, 0.f, 0.f};
        acc[j][1] = (f32x4){0.f, 0.f, 0.f, 0.f};
    }

    f32x4 L[8];

    // ---- prologue: stage chunk 0; invalid stagers zero their slots ONCE ----
    if (valid) {
#pragma unroll
        for (int j = 0; j < 8; ++j)
            L[j] = *(const f32x4*)(gp + (size_t)j * strideC);
#pragma unroll
        for (int i = 0; i < 4; ++i) {
            half8 hv;
#pragma unroll
            for (int k = 0; k < 8; ++k) hv[k] = (_Float16)L[k][i];
            *(half8*)(ld0 + i * AK) = hv;
        }
    } else if (stager) {
        const half8 z = (half8){0, 0, 0, 0, 0, 0, 0, 0};
#pragma unroll
        for (int i = 0; i < 4; ++i)
            *(half8*)(ld0 + i * AK) = z;
    }
    __syncthreads();

#pragma unroll 1
    for (int ch = 0; ch < NCHUNK; ++ch) {
        const bool more = (ch + 1 < NCHUNK);

        // ---- issue next chunk's loads (no waits: first use is after sync1) ----
        if (valid && more) {
            const float* g = gp + (size_t)(ch + 1) * KC * strideC;
#pragma unroll
            for (int j = 0; j < 8; ++j)
                L[j] = *(const f32x4*)(g + (size_t)j * strideC);
        }

        // ---- compute current chunk: this wave's (row, dy-half) ----
        {
            const half8 a = *(const half8*)&Ald[(wr * 16 + l15) * AK + quad * 8];
            if (wd == 0) {
#pragma unroll
                for (int j = 0; j < 5; ++j) {
                    const int r = wr + j;                // dy = j
                    const half8 b0 = *(const half8*)&Bld[(r * 32 + l15) * AK + quad * 8];
                    acc[j][0] = __builtin_amdgcn_mfma_f32_16x16x32_f16(a, b0, acc[j][0], 0, 0, 0);
                    const half8 b1 = *(const half8*)&Bld[(r * 32 + 16 + l15) * AK + quad * 8];
                    acc[j][1] = __builtin_amdgcn_mfma_f32_16x16x32_f16(a, b1, acc[j][1], 0, 0, 0);
                }
            } else {
#pragma unroll
                for (int j = 0; j < 4; ++j) {
                    const int r = wr + 5 + j;            // dy = 5 + j
                    const half8 b0 = *(const half8*)&Bld[(r * 32 + l15) * AK + quad * 8];
                    acc[j][0] = __builtin_amdgcn_mfma_f32_16x16x32_f16(a, b0, acc[j][0], 0, 0, 0);
                    const half8 b1 = *(const half8*)&Bld[(r * 32 + 16 + l15) * AK + quad * 8];
                    acc[j][1] = __builtin_amdgcn_mfma_f32_16x16x32_f16(a, b1, acc[j][1], 0, 0, 0);
                }
            }
        }

        if (more) {
            __syncthreads();   // all waves done reading LDS for chunk ch
            if (valid) {
#pragma unroll
                for (int i = 0; i < 4; ++i) {
                    half8 hv;
#pragma unroll
                    for (int k = 0; k < 8; ++k) hv[k] = (_Float16)L[k][i];
                    *(half8*)(ld0 + i * AK) = hv;
                }
            }
            __syncthreads();   // chunk ch+1 visible
        }
    }

    // ---- epilogue (r2-proven direct scatter): D[p][q], p=quad*4+reg,
    // q=l15+16*tt, dx=q-p; this wave stores its dy-half only ----
    const int h = h0 + wr;
    if (wd == 0) {
#pragma unroll
        for (int j = 0; j < 5; ++j) {
            const int dy = j;
#pragma unroll
            for (int tt = 0; tt < 2; ++tt) {
#pragma unroll
                for (int reg = 0; reg < 4; ++reg) {
                    const int p  = quad * 4 + reg;
                    const int dx = l15 + 16 * tt - p;
                    if (dx >= 0 && dx <= 8) {
                        out[(((size_t)b * KOUT + (dy * 9 + dx)) * HH + h) * WW + (w0 + p)] =
                            acc[j][tt][reg];
                    }
                }
            }
        }
    } else {
#pragma unroll
        for (int j = 0; j < 4; ++j) {
            const int dy = 5 + j;
#pragma unroll
            for (int tt = 0; tt < 2; ++tt) {
#pragma unroll
                for (int reg = 0; reg < 4; ++reg) {
                    const int p  = quad * 4 + reg;
                    const int dx = l15 + 16 * tt - p;
                    if (dx >= 0 && dx <= 8) {
                        out[(((size_t)b * KOUT + (dy * 9 + dx)) * HH + h) * WW + (w0 + p)] =
                            acc[j][tt][reg];
                    }
                }
            }
        }
    }
}

extern "C" void kernel_launch(void* const* d_in, const int* in_sizes, int n_in,
                              void* d_out, int out_size, void* d_ws, size_t ws_size,
                              hipStream_t stream)
{
    (void)in_sizes; (void)n_in; (void)d_ws; (void)ws_size; (void)out_size;
    const float* i1 = (const float*)d_in[0];
    const float* i2 = (const float*)d_in[1];
    float* out = (float*)d_out;

    dim3 grid(WW / SW, HH / TH, BB);   // (8, 32, 4) = 1024 blocks
    dim3 block(512);
    corr_mfma6<<<grid, block, 0, stream>>>(i1, i2, out);
}

// Round 6
// 185.344 us; speedup vs baseline: 1.1397x; 1.0252x over previous
//
#include <hip/hip_runtime.h>

#define BB   4
#define CC   256
#define HH   128
#define WW   128
#define PAD  4
#define KOUT 81

#define TH   4            // output rows per block (4 rows x 2 dy-halves = 8 waves)
#define SW   16           // output cols per block
#define KC   16           // channels per chunk (one MFMA 16x16x16 K)
#define NCHUNK (CC / KC)  // 16
#define AK   20           // halves per LDS point row (40 B; b64 reads conflict-light)
#define ABASE 0           // A region: 64 pts
#define BBASE (64 * AK)   // B region: 384 slots
#define LDSH  (BBASE + 384 * AK)   // 8960 halves per buffer

typedef _Float16 half4 __attribute__((ext_vector_type(4)));
typedef float    f32x4 __attribute__((ext_vector_type(4)));

// K=16 f16 MFMA: legacy builtin spelling (carried forward to gfx950).
// NOTE: no __has_builtin gating -- it reports false on the HIP host pass (r5 lesson).
#define MFMA16(a, b, c) __builtin_amdgcn_mfma_f32_16x16x16f16((a), (b), (c), 0, 0, 0)

// Raw barrier: explicit lgkmcnt(0) only. Unlike __syncthreads(), this does NOT
// make the compiler drain vmcnt(0) -- prefetched loads stay in flight across it.
#define BARRIER() do {                                        \
    asm volatile("s_waitcnt lgkmcnt(0)" ::: "memory");        \
    __builtin_amdgcn_s_barrier();                             \
    asm volatile("" ::: "memory");                            \
} while (0)

__device__ __forceinline__ void issue4(f32x4 (&L)[4], const float* g, size_t strideC)
{
    L[0] = *(const f32x4*)(g);
    L[1] = *(const f32x4*)(g + strideC);
    L[2] = *(const f32x4*)(g + 2 * strideC);
    L[3] = *(const f32x4*)(g + 3 * strideC);
}

__device__ __forceinline__ void convert4(const f32x4 (&L)[4], _Float16* dst)
{
#pragma unroll
    for (int i = 0; i < 4; ++i) {
        half4 hv;
        hv[0] = (_Float16)L[0][i];
        hv[1] = (_Float16)L[1][i];
        hv[2] = (_Float16)L[2][i];
        hv[3] = (_Float16)L[3][i];
        *(half4*)(dst + i * AK) = hv;
    }
}

__device__ __forceinline__ void compute_chunk(const _Float16* buf, f32x4 (&acc)[5][2],
                                              int wr, int wd, int l15, int quad)
{
    const half4 a = *(const half4*)&buf[ABASE + (wr * 16 + l15) * AK + quad * 4];
    if (wd == 0) {
#pragma unroll
        for (int j = 0; j < 5; ++j) {
            const int r = wr + j;                  // dy = j
            const half4 b0 = *(const half4*)&buf[BBASE + (r * 32 + l15) * AK + quad * 4];
            acc[j][0] = MFMA16(a, b0, acc[j][0]);
            const half4 b1 = *(const half4*)&buf[BBASE + (r * 32 + 16 + l15) * AK + quad * 4];
            acc[j][1] = MFMA16(a, b1, acc[j][1]);
        }
    } else {
#pragma unroll
        for (int j = 0; j < 4; ++j) {
            const int r = wr + 5 + j;              // dy = 5 + j
            const half4 b0 = *(const half4*)&buf[BBASE + (r * 32 + l15) * AK + quad * 4];
            acc[j][0] = MFMA16(a, b0, acc[j][0]);
            const half4 b1 = *(const half4*)&buf[BBASE + (r * 32 + 16 + l15) * AK + quad * 4];
            acc[j][1] = MFMA16(a, b1, acc[j][1]);
        }
    }
}

__global__ __launch_bounds__(512, 4)
void corr_mfma7(const float* __restrict__ i1,
                const float* __restrict__ i2,
                float* __restrict__ out)
{
    // Double-buffered LDS: [buf][A 64 pts | B 384 slots], AK-strided f16.
    // 2 x 8960 halves = 35840 B -> 2 blocks/CU fit (71.7 KB of 160 KB).
    __shared__ _Float16 lds[2][LDSH];

    const int t    = threadIdx.x;
    const int wave = t >> 6;
    const int lane = t & 63;
    const int l15  = lane & 15;
    const int quad = lane >> 4;
    const int wr   = wave >> 1;   // output row within tile (0..3)
    const int wd   = wave & 1;    // dy half

    // ---- XCD-chunked block swizzle (r2-proven) ----
    const int raw     = blockIdx.x + 8 * blockIdx.y + 256 * blockIdx.z;
    const int logical = (raw & 7) * 128 + (raw >> 3);   // bijective: 1024 = 8*128
    const int b  = logical >> 8;
    const int h0 = ((logical >> 3) & 31) * TH;
    const int w0 = (logical & 7) * SW;

    const size_t strideC = (size_t)HH * WW;
    const float* i1b = i1 + (size_t)b * CC * strideC;
    const float* i2b = i2 + (size_t)b * CC * strideC;

    // ---- staging: each stager owns a (4-col x 4-ch) granule ----
    // B: threads 0..287 = 12 rows x 6 col-groups x 4 ch4-groups
    // A: threads 288..351 = 4 rows x 4 col-groups x 4 ch4-groups
    // threads 352..511: compute-only.
    bool stager, valid;
    const float* gp;
    int ldoff;

    if (t < 288) {
        stager = true;
        const int g   = t % 6;
        const int t6  = t / 6;           // 0..47
        const int ch4 = t6 & 3;
        const int sr  = t6 >> 2;         // 0..11
        const int row  = h0 - PAD + sr;
        const int col0 = w0 - PAD + 4 * g;
        valid = (row >= 0) && (row < HH) && (col0 >= 0) && (col0 + 3 < WW);
        gp = i2b + (size_t)(valid ? row : 0) * WW + (valid ? col0 : 0)
                 + (size_t)ch4 * 4 * strideC;
        ldoff = BBASE + (sr * 32 + 4 * g) * AK + ch4 * 4;
    } else if (t < 352) {
        stager = true;
        const int i   = t - 288;
        const int g   = i & 3;
        const int t4  = i >> 2;          // 0..15
        const int ch4 = t4 & 3;
        const int sr  = t4 >> 2;         // 0..3
        valid = true;
        gp = i1b + (size_t)(h0 + sr) * WW + (w0 + 4 * g)
                 + (size_t)ch4 * 4 * strideC;
        ldoff = ABASE + (sr * 16 + 4 * g) * AK + ch4 * 4;
    } else {
        stager = false;
        valid  = false;
        gp    = i1b;
        ldoff = 0;
    }
    const bool sv = stager && valid;

    f32x4 acc[5][2];
#pragma unroll
    for (int j = 0; j < 5; ++j) {
        acc[j][0] = (f32x4){0.f, 0.f, 0.f, 0.f};
        acc[j][1] = (f32x4){0.f, 0.f, 0.f, 0.f};
    }

    f32x4 La[4], Lb[4];

    // ---- prologue ----
    if (stager && !valid) {
        // zero this granule's slots in BOTH buffers, once; never touched again
        const half4 z = (half4){0, 0, 0, 0};
#pragma unroll
        for (int i = 0; i < 4; ++i) {
            *(half4*)(&lds[0][ldoff + i * AK]) = z;
            *(half4*)(&lds[1][ldoff + i * AK]) = z;
        }
    }
    if (sv) {
        issue4(La, gp, strideC);                               // chunk 0
        issue4(Lb, gp + (size_t)KC * strideC, strideC);        // chunk 1
        convert4(La, &lds[0][ldoff]);                          // waits La only
    }
    BARRIER();   // chunk 0 ready; chunk 1 loads still in flight

    // ---- main loop: 8 chunk-pairs; depth-2 prefetch, counted vmcnt,
    //      ONE raw barrier per chunk, never vmcnt(0) in steady state ----
#pragma unroll 1
    for (int jp = 0; jp < 8; ++jp) {
        const int j = 2 * jp;

        // even chunk j: compute buf0, convert chunk j+1 -> buf1
        if (sv && (j + 2 < NCHUNK))
            issue4(La, gp + (size_t)(j + 2) * KC * strideC, strideC);
        compute_chunk(&lds[0][0], acc, wr, wd, l15, quad);
        if (sv)
            convert4(Lb, &lds[1][ldoff]);   // compiler waits Lb's 4 loads: vmcnt(4)
        BARRIER();

        // odd chunk j+1: compute buf1, convert chunk j+2 -> buf0
        if (sv && (j + 3 < NCHUNK))
            issue4(Lb, gp + (size_t)(j + 3) * KC * strideC, strideC);
        compute_chunk(&lds[1][0], acc, wr, wd, l15, quad);
        if (jp < 7) {
            if (sv)
                convert4(La, &lds[0][ldoff]);
            BARRIER();
        }
    }

    // ---- epilogue: D[p][q], p = quad*4+reg, q = l15 + 16*tt, dx = q - p ----
    const int h = h0 + wr;
    if (wd == 0) {
#pragma unroll
        for (int j = 0; j < 5; ++j) {
            const int dy = j;
#pragma unroll
            for (int tt = 0; tt < 2; ++tt) {
#pragma unroll
                for (int reg = 0; reg < 4; ++reg) {
                    const int p  = quad * 4 + reg;
                    const int dx = l15 + 16 * tt - p;
                    if (dx >= 0 && dx <= 8) {
                        out[(((size_t)b * KOUT + (dy * 9 + dx)) * HH + h) * WW + (w0 + p)] =
                            acc[j][tt][reg];
                    }
                }
            }
        }
    } else {
#pragma unroll
        for (int j = 0; j < 4; ++j) {
            const int dy = 5 + j;
#pragma unroll
            for (int tt = 0; tt < 2; ++tt) {
#pragma unroll
                for (int reg = 0; reg < 4; ++reg) {
                    const int p  = quad * 4 + reg;
                    const int dx = l15 + 16 * tt - p;
                    if (dx >= 0 && dx <= 8) {
                        out[(((size_t)b * KOUT + (dy * 9 + dx)) * HH + h) * WW + (w0 + p)] =
                            acc[j][tt][reg];
                    }
                }
            }
        }
    }
}

extern "C" void kernel_launch(void* const* d_in, const int* in_sizes, int n_in,
                              void* d_out, int out_size, void* d_ws, size_t ws_size,
                              hipStream_t stream)
{
    (void)in_sizes; (void)n_in; (void)d_ws; (void)ws_size; (void)out_size;
    const float* i1 = (const float*)d_in[0];
    const float* i2 = (const float*)d_in[1];
    float* out = (float*)d_out;

    dim3 grid(WW / SW, HH / TH, BB);   // (8, 32, 4) = 1024 blocks
    dim3 block(512);
    corr_mfma7<<<grid, block, 0, stream>>>(i1, i2, out);
}

// Round 7
// 180.761 us; speedup vs baseline: 1.1686x; 1.0254x over previous
//
#include <hip/hip_runtime.h>

#define BB   4
#define CC   256
#define HH   128
#define WW   128
#define PAD  4
#define KOUT 81

#define TH   8            // output rows per block (8 rows x 2 dy-halves = 16 waves)
#define SW   16           // output cols per block
#define KC   16           // channels per chunk (one MFMA 16x16x16 K)
#define NCHUNK (CC / KC)  // 16
#define AK   20           // halves per LDS point row (40 B)
#define ABASE 0           // A region: 128 pts
#define BBASE (128 * AK)  // B region: 512 slots (16 rows x 32; q<24 valid)
#define LDSH  (BBASE + 512 * AK)   // 12800 halves = 25600 B per buffer

typedef _Float16 half4 __attribute__((ext_vector_type(4)));
typedef float    f32x4 __attribute__((ext_vector_type(4)));

// K=16 f16 MFMA: legacy builtin spelling (no __has_builtin gating -- r5 lesson:
// it reports false on the HIP host pass and kills the build).
#define MFMA16(a, b, c) __builtin_amdgcn_mfma_f32_16x16x16f16((a), (b), (c), 0, 0, 0)

// Raw barrier: explicit lgkmcnt(0) only -- prefetched global loads stay in
// flight across it (no vmcnt(0) drain, unlike __syncthreads()).
#define BARRIER() do {                                        \
    asm volatile("s_waitcnt lgkmcnt(0)" ::: "memory");        \
    __builtin_amdgcn_s_barrier();                             \
    asm volatile("" ::: "memory");                            \
} while (0)

__device__ __forceinline__ void issue4(f32x4 (&L)[4], const float* g, size_t strideC)
{
    L[0] = *(const f32x4*)(g);
    L[1] = *(const f32x4*)(g + strideC);
    L[2] = *(const f32x4*)(g + 2 * strideC);
    L[3] = *(const f32x4*)(g + 3 * strideC);
}

__device__ __forceinline__ void convert4(const f32x4 (&L)[4], _Float16* dst)
{
#pragma unroll
    for (int i = 0; i < 4; ++i) {
        half4 hv;
        hv[0] = (_Float16)L[0][i];
        hv[1] = (_Float16)L[1][i];
        hv[2] = (_Float16)L[2][i];
        hv[3] = (_Float16)L[3][i];
        *(half4*)(dst + i * AK) = hv;
    }
}

__device__ __forceinline__ void compute_chunk(const _Float16* buf, f32x4 (&acc)[5][2],
                                              int wr, int wd, int l15, int quad)
{
    const half4 a = *(const half4*)&buf[ABASE + (wr * 16 + l15) * AK + quad * 4];
    if (wd == 0) {
#pragma unroll
        for (int j = 0; j < 5; ++j) {
            const int r = wr + j;                  // dy = j
            const half4 b0 = *(const half4*)&buf[BBASE + (r * 32 + l15) * AK + quad * 4];
            acc[j][0] = MFMA16(a, b0, acc[j][0]);
            const half4 b1 = *(const half4*)&buf[BBASE + (r * 32 + 16 + l15) * AK + quad * 4];
            acc[j][1] = MFMA16(a, b1, acc[j][1]);
        }
    } else {
#pragma unroll
        for (int j = 0; j < 4; ++j) {
            const int r = wr + 5 + j;              // dy = 5 + j
            const half4 b0 = *(const half4*)&buf[BBASE + (r * 32 + l15) * AK + quad * 4];
            acc[j][0] = MFMA16(a, b0, acc[j][0]);
            const half4 b1 = *(const half4*)&buf[BBASE + (r * 32 + 16 + l15) * AK + quad * 4];
            acc[j][1] = MFMA16(a, b1, acc[j][1]);
        }
    }
}

__global__ __launch_bounds__(1024, 4)
void corr_mfma8(const float* __restrict__ i1,
                const float* __restrict__ i2,
                float* __restrict__ out)
{
    // Double-buffered LDS: [buf][A 128 pts | B 512 slots], AK-strided f16.
    // 2 x 25600 B = 51200 B.
    __shared__ _Float16 lds[2][LDSH];

    const int t    = threadIdx.x;
    const int wave = t >> 6;      // 0..15
    const int lane = t & 63;
    const int l15  = lane & 15;
    const int quad = lane >> 4;
    const int wr   = wave >> 1;   // output row within tile (0..7)
    const int wd   = wave & 1;    // dy half: 0 -> dy 0..4, 1 -> dy 5..8

    // ---- XCD-chunked block swizzle (r2-proven) ----
    const int raw     = blockIdx.x + 8 * blockIdx.y + 128 * blockIdx.z;
    const int logical = (raw & 7) * 64 + (raw >> 3);   // bijective: 512 = 8*64
    const int b  = logical >> 7;
    const int h0 = ((logical >> 3) & 15) * TH;
    const int w0 = (logical & 7) * SW;

    const size_t strideC = (size_t)HH * WW;
    const float* i1b = i1 + (size_t)b * CC * strideC;
    const float* i2b = i2 + (size_t)b * CC * strideC;

    // ---- staging: threads 0..511 each own one (4-col x 4-ch) granule ----
    // B: threads 0..383 = 16 rows x 6 col-groups x 4 ch4-groups
    // A: threads 384..511 = 8 rows x 4 col-groups x 4 ch4-groups
    // threads 512..1023: compute-only.
    bool stager, valid;
    const float* gp;
    int ldoff;

    if (t < 384) {
        stager = true;
        const int g   = t % 6;
        const int t6  = t / 6;           // 0..63
        const int ch4 = t6 & 3;
        const int sr  = t6 >> 2;         // 0..15
        const int row  = h0 - PAD + sr;
        const int col0 = w0 - PAD + 4 * g;
        valid = (row >= 0) && (row < HH) && (col0 >= 0) && (col0 + 3 < WW);
        gp = i2b + (size_t)(valid ? row : 0) * WW + (valid ? col0 : 0)
                 + (size_t)ch4 * 4 * strideC;
        ldoff = BBASE + (sr * 32 + 4 * g) * AK + ch4 * 4;
    } else if (t < 512) {
        stager = true;
        const int i   = t - 384;
        const int g   = i & 3;
        const int t4  = i >> 2;          // 0..31
        const int ch4 = t4 & 3;
        const int sr  = t4 >> 2;         // 0..7
        valid = true;
        gp = i1b + (size_t)(h0 + sr) * WW + (w0 + 4 * g)
                 + (size_t)ch4 * 4 * strideC;
        ldoff = ABASE + (sr * 16 + 4 * g) * AK + ch4 * 4;
    } else {
        stager = false;
        valid  = false;
        gp    = i1b;
        ldoff = 0;
    }
    const bool sv = stager && valid;

    f32x4 acc[5][2];
#pragma unroll
    for (int j = 0; j < 5; ++j) {
        acc[j][0] = (f32x4){0.f, 0.f, 0.f, 0.f};
        acc[j][1] = (f32x4){0.f, 0.f, 0.f, 0.f};
    }

    f32x4 La[4], Lb[4];

    // ---- prologue ----
    if (stager && !valid) {
        // zero this granule's slots in BOTH buffers, once; never touched again
        const half4 z = (half4){0, 0, 0, 0};
#pragma unroll
        for (int i = 0; i < 4; ++i) {
            *(half4*)(&lds[0][ldoff + i * AK]) = z;
            *(half4*)(&lds[1][ldoff + i * AK]) = z;
        }
    }
    if (sv) {
        issue4(La, gp, strideC);                               // chunk 0
        issue4(Lb, gp + (size_t)KC * strideC, strideC);        // chunk 1
        convert4(La, &lds[0][ldoff]);                          // waits La only
    }
    BARRIER();   // chunk 0 ready; chunk 1 loads still in flight

    // ---- main loop: 8 chunk-pairs; depth-2 prefetch, counted vmcnt,
    //      ONE raw barrier per chunk, never vmcnt(0) in steady state ----
#pragma unroll 1
    for (int jp = 0; jp < 8; ++jp) {
        const int j = 2 * jp;

        // even chunk j: compute buf0, convert chunk j+1 -> buf1
        if (sv && (j + 2 < NCHUNK))
            issue4(La, gp + (size_t)(j + 2) * KC * strideC, strideC);
        compute_chunk(&lds[0][0], acc, wr, wd, l15, quad);
        if (sv)
            convert4(Lb, &lds[1][ldoff]);   // waits Lb's 4 loads: vmcnt(4)
        BARRIER();

        // odd chunk j+1: compute buf1, convert chunk j+2 -> buf0
        if (sv && (j + 3 < NCHUNK))
            issue4(Lb, gp + (size_t)(j + 3) * KC * strideC, strideC);
        compute_chunk(&lds[1][0], acc, wr, wd, l15, quad);
        if (jp < 7) {
            if (sv)
                convert4(La, &lds[0][ldoff]);
            BARRIER();
        }
    }

    // ---- epilogue: D[p][q], p = quad*4+reg, q = l15 + 16*tt, dx = q - p ----
    const int h = h0 + wr;
    if (wd == 0) {
#pragma unroll
        for (int j = 0; j < 5; ++j) {
            const int dy = j;
#pragma unroll
            for (int tt = 0; tt < 2; ++tt) {
#pragma unroll
                for (int reg = 0; reg < 4; ++reg) {
                    const int p  = quad * 4 + reg;
                    const int dx = l15 + 16 * tt - p;
                    if (dx >= 0 && dx <= 8) {
                        out[(((size_t)b * KOUT + (dy * 9 + dx)) * HH + h) * WW + (w0 + p)] =
                            acc[j][tt][reg];
                    }
                }
            }
        }
    } else {
#pragma unroll
        for (int j = 0; j < 4; ++j) {
            const int dy = 5 + j;
#pragma unroll
            for (int tt = 0; tt < 2; ++tt) {
#pragma unroll
                for (int reg = 0; reg < 4; ++reg) {
                    const int p  = quad * 4 + reg;
                    const int dx = l15 + 16 * tt - p;
                    if (dx >= 0 && dx <= 8) {
                        out[(((size_t)b * KOUT + (dy * 9 + dx)) * HH + h) * WW + (w0 + p)] =
                            acc[j][tt][reg];
                    }
                }
            }
        }
    }
}

extern "C" void kernel_launch(void* const* d_in, const int* in_sizes, int n_in,
                              void* d_out, int out_size, void* d_ws, size_t ws_size,
                              hipStream_t stream)
{
    (void)in_sizes; (void)n_in; (void)d_ws; (void)ws_size; (void)out_size;
    const float* i1 = (const float*)d_in[0];
    const float* i2 = (const float*)d_in[1];
    float* out = (float*)d_out;

    dim3 grid(WW / SW, HH / TH, BB);   // (8, 16, 4) = 512 blocks
    dim3 block(1024);
    corr_mfma8<<<grid, block, 0, stream>>>(i1, i2, out);
}